// Round 2
// baseline (434.191 us; speedup 1.0000x reference)
//
#include <hip/hip_runtime.h>

#define G 128
#define D_OUT 16
#define BIN_SHIFT 3              // 8 cells per bin per dim
#define NBINS (16 * 16 * 16)     // (128>>3)^3

// ---------- shared helpers ----------

__device__ __forceinline__ void stage_grids(const float* __restrict__ xs0,
                                            const float* __restrict__ xs1,
                                            const float* __restrict__ xs2,
                                            float (*sxs)[G], int tid, int nthreads)
{
    for (int i = tid; i < 3 * G; i += nthreads) {
        float v;
        if (i < G)            v = xs0[i];
        else if (i < 2 * G)   v = xs1[i - G];
        else                  v = xs2[i - 2 * G];
        (&sxs[0][0])[i] = v;
    }
}

// largest idx with g[idx] <= clamp(v); also fractional coordinate t
__device__ __forceinline__ void search1(const float* __restrict__ g, float v,
                                        int& li, float& t)
{
    v = fminf(fmaxf(v, g[0]), g[G - 1]);
    int idx = 0;
    #pragma unroll
    for (int s = 64; s >= 1; s >>= 1) {
        int cand = idx + s;
        if (g[cand] <= v) idx = cand;
    }
    if (idx > G - 2) idx = G - 2;
    li = idx;
    t  = (v - g[idx]) / (g[idx + 1] - g[idx]);
}

__device__ __forceinline__ int bin_of(int li0, int li1, int li2)
{
    return ((li0 >> BIN_SHIFT) << 8) | ((li1 >> BIN_SHIFT) << 4) | (li2 >> BIN_SHIFT);
}

// ---------- pass 1: histogram ----------

__global__ __launch_bounds__(256) void hist_kernel(
    const float* __restrict__ x,
    const float* __restrict__ xs0, const float* __restrict__ xs1, const float* __restrict__ xs2,
    unsigned int* __restrict__ counts, int n)
{
    __shared__ float sxs[3][G];
    stage_grids(xs0, xs1, xs2, sxs, threadIdx.x, 256);
    __syncthreads();

    int q = blockIdx.x * 256 + threadIdx.x;
    if (q >= n) return;
    int li[3]; float t;
    #pragma unroll
    for (int d = 0; d < 3; ++d) search1(sxs[d], x[q * 3 + d], li[d], t);
    atomicAdd(&counts[bin_of(li[0], li[1], li[2])], 1u);
}

// ---------- pass 2: exclusive scan over 4096 counts (single block) ----------

__global__ __launch_bounds__(1024) void scan_kernel(
    const unsigned int* __restrict__ counts, unsigned int* __restrict__ offsets)
{
    __shared__ unsigned int sd[1024];
    const int t = threadIdx.x;
    uint4 c = ((const uint4*)counts)[t];
    unsigned int s = c.x + c.y + c.z + c.w;
    sd[t] = s;
    __syncthreads();
    for (int off = 1; off < 1024; off <<= 1) {
        unsigned int v = sd[t];
        unsigned int add = (t >= off) ? sd[t - off] : 0u;
        __syncthreads();
        sd[t] = v + add;
        __syncthreads();
    }
    unsigned int excl = sd[t] - s;
    uint4 o;
    o.x = excl;
    o.y = o.x + c.x;
    o.z = o.y + c.y;
    o.w = o.z + c.z;
    ((uint4*)offsets)[t] = o;
}

// ---------- pass 3: scatter payloads into bin-sorted order ----------

__global__ __launch_bounds__(256) void scatter_kernel(
    const float* __restrict__ x,
    const float* __restrict__ xs0, const float* __restrict__ xs1, const float* __restrict__ xs2,
    unsigned int* __restrict__ offsets, float4* __restrict__ payload, int n)
{
    __shared__ float sxs[3][G];
    stage_grids(xs0, xs1, xs2, sxs, threadIdx.x, 256);
    __syncthreads();

    int q = blockIdx.x * 256 + threadIdx.x;
    if (q >= n) return;
    float v0 = x[q * 3 + 0], v1 = x[q * 3 + 1], v2 = x[q * 3 + 2];
    int li[3]; float t;
    search1(sxs[0], v0, li[0], t);
    search1(sxs[1], v1, li[1], t);
    search1(sxs[2], v2, li[2], t);
    unsigned int slot = atomicAdd(&offsets[bin_of(li[0], li[1], li[2])], 1u);
    payload[slot] = make_float4(v0, v1, v2, __uint_as_float((unsigned int)q));
}

// ---------- pass 4: interpolate the sorted stream ----------

__global__ __launch_bounds__(256) void interp_sorted_kernel(
    const float4* __restrict__ payload,
    const float* __restrict__ y,
    const float* __restrict__ xs0, const float* __restrict__ xs1, const float* __restrict__ xs2,
    float* __restrict__ out, int n)
{
    __shared__ float sxs[3][G];
    stage_grids(xs0, xs1, xs2, sxs, threadIdx.x, 256);
    __syncthreads();

    // XCD-aware swizzle: consecutive sorted chunks stay on one XCD's L2.
    int bid = blockIdx.x;
    int nb  = gridDim.x;
    if ((nb & 7) == 0) {
        int chunk = nb >> 3;
        bid = (bid & 7) * chunk + (bid >> 3);
    }

    const int i = bid * 64 + (threadIdx.x >> 2);
    if (i >= n) return;
    const int cg = (threadIdx.x & 3) * 4;

    const float4 p = payload[i];
    const unsigned int q = __float_as_uint(p.w);

    int   li[3];
    float t[3];
    search1(sxs[0], p.x, li[0], t[0]);
    search1(sxs[1], p.y, li[1], t[1]);
    search1(sxs[2], p.z, li[2], t[2]);

    const float w0[3] = { 1.f - t[0], 1.f - t[1], 1.f - t[2] };
    const float w1[3] = { t[0], t[1], t[2] };

    float4 acc = make_float4(0.f, 0.f, 0.f, 0.f);
    #pragma unroll
    for (int e = 0; e < 8; ++e) {
        const int e0 = (e >> 2) & 1, e1 = (e >> 1) & 1, e2 = e & 1;
        const float w = (e0 ? w1[0] : w0[0]) * (e1 ? w1[1] : w0[1]) * (e2 ? w1[2] : w0[2]);
        const int idx = ((li[0] + e0) * G + (li[1] + e1)) * G + (li[2] + e2);
        const float4 v = *(const float4*)(y + (size_t)idx * D_OUT + cg);
        acc.x += w * v.x;
        acc.y += w * v.y;
        acc.z += w * v.z;
        acc.w += w * v.w;
    }

    *(float4*)(out + (size_t)q * D_OUT + cg) = acc;
}

// ---------- fallback: direct (unsorted) kernel, known-good from R1 ----------

__global__ __launch_bounds__(256) void interp3d_kernel(
    const float* __restrict__ x, const float* __restrict__ y,
    const float* __restrict__ xs0, const float* __restrict__ xs1, const float* __restrict__ xs2,
    float* __restrict__ out, int nquery)
{
    __shared__ float sxs[3][G];
    stage_grids(xs0, xs1, xs2, sxs, threadIdx.x, 256);
    __syncthreads();

    const int q = blockIdx.x * 64 + (threadIdx.x >> 2);
    if (q >= nquery) return;
    const int cg = (threadIdx.x & 3) * 4;

    int li[3]; float t[3];
    #pragma unroll
    for (int d = 0; d < 3; ++d) search1(sxs[d], x[q * 3 + d], li[d], t[d]);

    const float w0[3] = { 1.f - t[0], 1.f - t[1], 1.f - t[2] };
    const float w1[3] = { t[0], t[1], t[2] };

    float4 acc = make_float4(0.f, 0.f, 0.f, 0.f);
    #pragma unroll
    for (int e = 0; e < 8; ++e) {
        const int e0 = (e >> 2) & 1, e1 = (e >> 1) & 1, e2 = e & 1;
        const float w = (e0 ? w1[0] : w0[0]) * (e1 ? w1[1] : w0[1]) * (e2 ? w1[2] : w0[2]);
        const int idx = ((li[0] + e0) * G + (li[1] + e1)) * G + (li[2] + e2);
        const float4 v = *(const float4*)(y + (size_t)idx * D_OUT + cg);
        acc.x += w * v.x; acc.y += w * v.y; acc.z += w * v.z; acc.w += w * v.w;
    }
    *(float4*)(out + (size_t)q * D_OUT + cg) = acc;
}

extern "C" void kernel_launch(void* const* d_in, const int* in_sizes, int n_in,
                              void* d_out, int out_size, void* d_ws, size_t ws_size,
                              hipStream_t stream) {
    const float* x   = (const float*)d_in[0];
    const float* y   = (const float*)d_in[1];
    const float* xs0 = (const float*)d_in[2];
    const float* xs1 = (const float*)d_in[3];
    const float* xs2 = (const float*)d_in[4];
    float* out = (float*)d_out;

    const int nquery = in_sizes[0] / 3;

    const size_t need = (size_t)2 * NBINS * sizeof(unsigned int)
                      + (size_t)nquery * sizeof(float4);
    if (ws_size < need) {
        // workspace too small: direct path
        const int blocks = (nquery + 63) / 64;
        hipLaunchKernelGGL(interp3d_kernel, dim3(blocks), dim3(256), 0, stream,
                           x, y, xs0, xs1, xs2, out, nquery);
        return;
    }

    unsigned int* counts  = (unsigned int*)d_ws;
    unsigned int* offsets = counts + NBINS;
    float4*       payload = (float4*)(offsets + NBINS);

    hipMemsetAsync(counts, 0, NBINS * sizeof(unsigned int), stream);

    const int b256 = (nquery + 255) / 256;
    hipLaunchKernelGGL(hist_kernel, dim3(b256), dim3(256), 0, stream,
                       x, xs0, xs1, xs2, counts, nquery);
    hipLaunchKernelGGL(scan_kernel, dim3(1), dim3(1024), 0, stream,
                       counts, offsets);
    hipLaunchKernelGGL(scatter_kernel, dim3(b256), dim3(256), 0, stream,
                       x, xs0, xs1, xs2, offsets, payload, nquery);

    const int b64 = (nquery + 63) / 64;
    hipLaunchKernelGGL(interp_sorted_kernel, dim3(b64), dim3(256), 0, stream,
                       payload, y, xs0, xs1, xs2, out, nquery);
}

// Round 3
// 94.929 us; speedup vs baseline: 4.5739x; 4.5739x over previous
//
#include <hip/hip_runtime.h>

#define G 128
#define D_OUT 16
#define BIN_SHIFT 3              // 8 cells per bin per dim
#define NBINS (16 * 16 * 16)     // 4096
#define NBLK 256                 // blocks for hist/scatter passes

// ---------- shared helpers ----------

__device__ __forceinline__ void stage_grids(const float* __restrict__ xs0,
                                            const float* __restrict__ xs1,
                                            const float* __restrict__ xs2,
                                            float (*sxs)[G], int tid, int nthreads)
{
    for (int i = tid; i < 3 * G; i += nthreads) {
        float v;
        if (i < G)            v = xs0[i];
        else if (i < 2 * G)   v = xs1[i - G];
        else                  v = xs2[i - 2 * G];
        (&sxs[0][0])[i] = v;
    }
}

// largest idx with g[idx] <= clamp(v); also fractional coordinate t
__device__ __forceinline__ void search1(const float* __restrict__ g, float v,
                                        int& li, float& t)
{
    v = fminf(fmaxf(v, g[0]), g[G - 1]);
    int idx = 0;
    #pragma unroll
    for (int s = 64; s >= 1; s >>= 1) {
        int cand = idx + s;
        if (g[cand] <= v) idx = cand;
    }
    if (idx > G - 2) idx = G - 2;
    li = idx;
    t  = (v - g[idx]) / (g[idx + 1] - g[idx]);
}

__device__ __forceinline__ int bin_of(int li0, int li1, int li2)
{
    return ((li0 >> BIN_SHIFT) << 8) | ((li1 >> BIN_SHIFT) << 4) | (li2 >> BIN_SHIFT);
}

// ---------- pass 1: per-block LDS histogram, atomic-free global flush ----------

__global__ __launch_bounds__(256) void hist_kernel(
    const float* __restrict__ x,
    const float* __restrict__ xs0, const float* __restrict__ xs1, const float* __restrict__ xs2,
    unsigned int* __restrict__ counts,   // [NBLK][NBINS]
    int n, int qpb)
{
    __shared__ float sxs[3][G];
    __shared__ unsigned int hist[NBINS];
    const int tid = threadIdx.x, blk = blockIdx.x;

    stage_grids(xs0, xs1, xs2, sxs, tid, 256);
    for (int i = tid; i < NBINS; i += 256) hist[i] = 0u;
    __syncthreads();

    const int q0 = blk * qpb, q1 = min(n, q0 + qpb);
    for (int q = q0 + tid; q < q1; q += 256) {
        int li[3]; float t;
        #pragma unroll
        for (int d = 0; d < 3; ++d) search1(sxs[d], x[q * 3 + d], li[d], t);
        atomicAdd(&hist[bin_of(li[0], li[1], li[2])], 1u);   // LDS atomic
    }
    __syncthreads();

    for (int i = tid; i < NBINS; i += 256)
        counts[(size_t)blk * NBINS + i] = hist[i];           // coalesced
}

// ---------- pass 2a: per-bin exclusive scan across the 256 block-rows ----------

__global__ __launch_bounds__(256) void scan_block_kernel(
    const unsigned int* __restrict__ counts,   // [NBLK][NBINS]
    unsigned int* __restrict__ offs,           // [NBLK][NBINS] exclusive within bin
    unsigned int* __restrict__ totals)         // [NBINS]
{
    __shared__ unsigned int sd[NBLK];
    const int b = blockIdx.x, k = threadIdx.x;
    const unsigned int v = counts[(size_t)k * NBINS + b];
    sd[k] = v;
    __syncthreads();
    for (int off = 1; off < NBLK; off <<= 1) {
        unsigned int t = sd[k];
        unsigned int a = (k >= off) ? sd[k - off] : 0u;
        __syncthreads();
        sd[k] = t + a;
        __syncthreads();
    }
    const unsigned int incl = sd[k];
    offs[(size_t)k * NBINS + b] = incl - v;
    if (k == NBLK - 1) totals[b] = incl;
}

// ---------- pass 2b: exclusive scan over 4096 bin totals (single block) ----------

__global__ __launch_bounds__(1024) void scan_totals_kernel(
    const unsigned int* __restrict__ totals, unsigned int* __restrict__ bin_base)
{
    __shared__ unsigned int sd[1024];
    const int t = threadIdx.x;
    uint4 c = ((const uint4*)totals)[t];
    unsigned int s = c.x + c.y + c.z + c.w;
    sd[t] = s;
    __syncthreads();
    for (int off = 1; off < 1024; off <<= 1) {
        unsigned int v = sd[t];
        unsigned int add = (t >= off) ? sd[t - off] : 0u;
        __syncthreads();
        sd[t] = v + add;
        __syncthreads();
    }
    unsigned int excl = sd[t] - s;
    uint4 o;
    o.x = excl;
    o.y = o.x + c.x;
    o.z = o.y + c.y;
    o.w = o.z + c.z;
    ((uint4*)bin_base)[t] = o;
}

// ---------- pass 3: deterministic scatter (LDS counters only) ----------

__global__ __launch_bounds__(256) void scatter_kernel(
    const float* __restrict__ x,
    const float* __restrict__ xs0, const float* __restrict__ xs1, const float* __restrict__ xs2,
    const unsigned int* __restrict__ offs,      // [NBLK][NBINS]
    const unsigned int* __restrict__ bin_base,  // [NBINS]
    float4* __restrict__ payload, int n, int qpb)
{
    __shared__ float sxs[3][G];
    __shared__ unsigned int base[NBINS];
    const int tid = threadIdx.x, blk = blockIdx.x;

    stage_grids(xs0, xs1, xs2, sxs, tid, 256);
    for (int i = tid; i < NBINS; i += 256)
        base[i] = bin_base[i] + offs[(size_t)blk * NBINS + i];
    __syncthreads();

    const int q0 = blk * qpb, q1 = min(n, q0 + qpb);
    for (int q = q0 + tid; q < q1; q += 256) {
        float v0 = x[q * 3 + 0], v1 = x[q * 3 + 1], v2 = x[q * 3 + 2];
        int li0, li1, li2; float t;
        search1(sxs[0], v0, li0, t);
        search1(sxs[1], v1, li1, t);
        search1(sxs[2], v2, li2, t);
        unsigned int slot = atomicAdd(&base[bin_of(li0, li1, li2)], 1u);  // LDS atomic
        payload[slot] = make_float4(v0, v1, v2, __uint_as_float((unsigned int)q));
    }
}

// ---------- pass 4: interpolate the bin-sorted stream ----------

__global__ __launch_bounds__(256) void interp_sorted_kernel(
    const float4* __restrict__ payload,
    const float* __restrict__ y,
    const float* __restrict__ xs0, const float* __restrict__ xs1, const float* __restrict__ xs2,
    float* __restrict__ out, int n)
{
    __shared__ float sxs[3][G];
    stage_grids(xs0, xs1, xs2, sxs, threadIdx.x, 256);
    __syncthreads();

    // XCD-aware swizzle: consecutive sorted chunks stay on one XCD's L2.
    int bid = blockIdx.x;
    int nb  = gridDim.x;
    if ((nb & 7) == 0) {
        int chunk = nb >> 3;
        bid = (bid & 7) * chunk + (bid >> 3);
    }

    const int i = bid * 64 + (threadIdx.x >> 2);
    if (i >= n) return;
    const int cg = (threadIdx.x & 3) * 4;

    const float4 p = payload[i];
    const unsigned int q = __float_as_uint(p.w);

    int li[3]; float t[3];
    search1(sxs[0], p.x, li[0], t[0]);
    search1(sxs[1], p.y, li[1], t[1]);
    search1(sxs[2], p.z, li[2], t[2]);

    const float w0[3] = { 1.f - t[0], 1.f - t[1], 1.f - t[2] };
    const float w1[3] = { t[0], t[1], t[2] };

    float4 acc = make_float4(0.f, 0.f, 0.f, 0.f);
    #pragma unroll
    for (int e = 0; e < 8; ++e) {
        const int e0 = (e >> 2) & 1, e1 = (e >> 1) & 1, e2 = e & 1;
        const float w = (e0 ? w1[0] : w0[0]) * (e1 ? w1[1] : w0[1]) * (e2 ? w1[2] : w0[2]);
        const int idx = ((li[0] + e0) * G + (li[1] + e1)) * G + (li[2] + e2);
        const float4 v = *(const float4*)(y + (size_t)idx * D_OUT + cg);
        acc.x += w * v.x; acc.y += w * v.y; acc.z += w * v.z; acc.w += w * v.w;
    }
    *(float4*)(out + (size_t)q * D_OUT + cg) = acc;
}

// ---------- fallback: direct (unsorted) kernel, known-good from R1 ----------

__global__ __launch_bounds__(256) void interp3d_kernel(
    const float* __restrict__ x, const float* __restrict__ y,
    const float* __restrict__ xs0, const float* __restrict__ xs1, const float* __restrict__ xs2,
    float* __restrict__ out, int nquery)
{
    __shared__ float sxs[3][G];
    stage_grids(xs0, xs1, xs2, sxs, threadIdx.x, 256);
    __syncthreads();

    const int q = blockIdx.x * 64 + (threadIdx.x >> 2);
    if (q >= nquery) return;
    const int cg = (threadIdx.x & 3) * 4;

    int li[3]; float t[3];
    #pragma unroll
    for (int d = 0; d < 3; ++d) search1(sxs[d], x[q * 3 + d], li[d], t[d]);

    const float w0[3] = { 1.f - t[0], 1.f - t[1], 1.f - t[2] };
    const float w1[3] = { t[0], t[1], t[2] };

    float4 acc = make_float4(0.f, 0.f, 0.f, 0.f);
    #pragma unroll
    for (int e = 0; e < 8; ++e) {
        const int e0 = (e >> 2) & 1, e1 = (e >> 1) & 1, e2 = e & 1;
        const float w = (e0 ? w1[0] : w0[0]) * (e1 ? w1[1] : w0[1]) * (e2 ? w1[2] : w0[2]);
        const int idx = ((li[0] + e0) * G + (li[1] + e1)) * G + (li[2] + e2);
        const float4 v = *(const float4*)(y + (size_t)idx * D_OUT + cg);
        acc.x += w * v.x; acc.y += w * v.y; acc.z += w * v.z; acc.w += w * v.w;
    }
    *(float4*)(out + (size_t)q * D_OUT + cg) = acc;
}

extern "C" void kernel_launch(void* const* d_in, const int* in_sizes, int n_in,
                              void* d_out, int out_size, void* d_ws, size_t ws_size,
                              hipStream_t stream) {
    const float* x   = (const float*)d_in[0];
    const float* y   = (const float*)d_in[1];
    const float* xs0 = (const float*)d_in[2];
    const float* xs1 = (const float*)d_in[3];
    const float* xs2 = (const float*)d_in[4];
    float* out = (float*)d_out;

    const int nquery = in_sizes[0] / 3;

    // workspace layout
    const size_t counts_elems = (size_t)NBLK * NBINS;           // 1M uints = 4MB
    const size_t need = (2 * counts_elems + 2 * NBINS) * sizeof(unsigned int)
                      + (size_t)nquery * sizeof(float4);
    if (ws_size < need) {
        const int blocks = (nquery + 63) / 64;
        hipLaunchKernelGGL(interp3d_kernel, dim3(blocks), dim3(256), 0, stream,
                           x, y, xs0, xs1, xs2, out, nquery);
        return;
    }

    unsigned int* counts   = (unsigned int*)d_ws;
    unsigned int* offs     = counts + counts_elems;
    unsigned int* totals   = offs + counts_elems;
    unsigned int* bin_base = totals + NBINS;
    float4*       payload  = (float4*)(bin_base + NBINS);

    const int qpb = (nquery + NBLK - 1) / NBLK;

    hipLaunchKernelGGL(hist_kernel, dim3(NBLK), dim3(256), 0, stream,
                       x, xs0, xs1, xs2, counts, nquery, qpb);
    hipLaunchKernelGGL(scan_block_kernel, dim3(NBINS), dim3(NBLK), 0, stream,
                       counts, offs, totals);
    hipLaunchKernelGGL(scan_totals_kernel, dim3(1), dim3(1024), 0, stream,
                       totals, bin_base);
    hipLaunchKernelGGL(scatter_kernel, dim3(NBLK), dim3(256), 0, stream,
                       x, xs0, xs1, xs2, offs, bin_base, payload, nquery, qpb);

    const int b64 = (nquery + 63) / 64;
    hipLaunchKernelGGL(interp_sorted_kernel, dim3(b64), dim3(256), 0, stream,
                       payload, y, xs0, xs1, xs2, out, nquery);
}